// Round 13
// baseline (59.985 us; speedup 1.0000x reference)
//
#include <hip/hip_runtime.h>
#include <math.h>

#define BATCH 8
#define T 2048
#define N 256        // STATE
#define INF 128      // IN
#define OUTF 128     // OUT
#define L 16         // chunk length
#define LOG2L 4
#define NC (T / L)   // 128 chunks
#define KTOT 640     // K for k3 = 256 (Xr) + 256 (Xi) + 128 (u)
#define NKS 20       // KTOT / 32  (C-hat K-steps)
#define NKU 4        // INF / 32   (Bh K-steps)
#define UBS 516      // padded fp32 col-stride for kU uB tile

typedef __attribute__((ext_vector_type(8))) short short8;
typedef __attribute__((ext_vector_type(4))) float f32x4;

__device__ __forceinline__ unsigned short f2b(float f) {   // fp32 -> bf16 RTNE
    union { float f; unsigned u; } x; x.f = f;
    unsigned r = (x.u + 0x7FFFu + ((x.u >> 16) & 1u)) >> 16;
    return (unsigned short)r;
}
__device__ __forceinline__ float b2f(unsigned short s) {
    union { unsigned u; float f; } x; x.u = ((unsigned)s) << 16;
    return x.f;
}

// ---------------- K_PREP: Apow + C-hat frags (Bswz) + Bh frags (Bswz2) ----------------
__global__ __launch_bounds__(256) void k_prep(const float* __restrict__ Are,
                                              const float* __restrict__ Aim,
                                              const float* __restrict__ Bre,
                                              const float* __restrict__ Bim,
                                              const float* __restrict__ Cre,
                                              const float* __restrict__ Cim,
                                              const float* __restrict__ D,
                                              float2* __restrict__ Apow,
                                              unsigned short* __restrict__ Bswz,
                                              unsigned short* __restrict__ Bswz2) {
    int blk = blockIdx.x;
    int tid = threadIdx.x;
    if (blk < 40) {
        int unit = blk * 4 + (tid >> 6);     // 0..159 = ks*8 + ot
        int ks = unit >> 3, ot = unit & 7;
        int l = tid & 63;
        int o = ot * 16 + (l & 15);
        int k0 = ks * 32 + (l >> 4) * 8;
        short8 out;
#pragma unroll
        for (int j = 0; j < 8; ++j) {
            int gk = k0 + j;
            float v = (gk < 256) ? Cre[gk * OUTF + o]
                    : (gk < 512) ? -Cim[(gk - 256) * OUTF + o]
                                 : D[(gk - 512) * OUTF + o];
            out[j] = (short)f2b(v);
        }
        *(short8*)(Bswz + ((size_t)unit * 64 + l) * 8) = out;
    } else if (blk < 72) {
        int unit = (blk - 40) * 4 + (tid >> 6);   // 0..127 = ks*32 + ct
        int l = tid & 63;
        int col = (unit & 31) * 16 + (l & 15);
        int k0 = (unit >> 5) * 32 + (l >> 4) * 8;
        short8 out;
#pragma unroll
        for (int j = 0; j < 8; ++j) {
            int gk = k0 + j;
            float v = (col < 256) ? Bre[gk * N + col] : Bim[gk * N + col - 256];
            out[j] = (short)f2b(v);
        }
        *(short8*)(Bswz2 + ((size_t)unit * 64 + l) * 8) = out;
    } else {
        int n = tid;
        float ar = Are[n], ai = Aim[n];
        float inv = 1.0f / sqrtf(ar * ar + ai * ai + 1.0f);
        ar *= inv; ai *= inv;
        float pr = ar, pi = ai;
        for (int j = 0; j < L; ++j) {
            Apow[j * N + n] = make_float2(pr, pi);   // A^(j+1)
            float nr = pr * ar - pi * ai;
            float ni = pr * ai + pi * ar;
            pr = nr; pi = ni;
        }
    }
}

// ---------------- KU: uB = u @ Bh via MFMA, then chunk-local scan ----------------
// grid 1024 blocks x 512 threads (8 waves). Block = ONE chunk: 16 rows x 512 cols.
__global__ __launch_bounds__(512, 8) void kU_scan(const float* __restrict__ u,
                                                  const unsigned short* __restrict__ Bswz2,
                                                  const float2* __restrict__ Apow,
                                                  unsigned short* __restrict__ xbb,
                                                  float2* __restrict__ carr) {
    __shared__ float uB[16][UBS];      // 33 KB
    int tid = threadIdx.x;
    int lane = tid & 63;
    int w = tid >> 6;
    size_t rowg0 = (size_t)blockIdx.x * 16;          // chunk start row
    const float* uprow = u + (rowg0 + (lane & 15)) * INF + (lane >> 4) * 8;

    f32x4 acc[4];
#pragma unroll
    for (int i = 0; i < 4; ++i) acc[i] = (f32x4){0.f, 0.f, 0.f, 0.f};

    const short8* Bfr2 = (const short8*)Bswz2;
#pragma unroll
    for (int ks = 0; ks < NKU; ++ks) {
        float4 a0 = *(const float4*)(uprow + ks * 32);
        float4 a1 = *(const float4*)(uprow + ks * 32 + 4);
        short8 af;
        af[0] = (short)f2b(a0.x); af[1] = (short)f2b(a0.y);
        af[2] = (short)f2b(a0.z); af[3] = (short)f2b(a0.w);
        af[4] = (short)f2b(a1.x); af[5] = (short)f2b(a1.y);
        af[6] = (short)f2b(a1.z); af[7] = (short)f2b(a1.w);
#pragma unroll
        for (int i = 0; i < 4; ++i) {
            int ct = w * 4 + i;
            short8 bf = Bfr2[(size_t)(ks * 32 + ct) * 64 + lane];
            acc[i] = __builtin_amdgcn_mfma_f32_16x16x32_bf16(af, bf, acc[i], 0, 0, 0);
        }
    }
    {   // spill: C/D layout row = (lane>>4)*4 + r, col = tile*16 + (lane&15)
        int rbase = (lane >> 4) * 4;
        int cb = lane & 15;
#pragma unroll
        for (int i = 0; i < 4; ++i) {
            int col = (w * 4 + i) * 16 + cb;
#pragma unroll
            for (int r = 0; r < 4; ++r)
                uB[rbase + r][col] = acc[i][r];
        }
    }
    __syncthreads();

    if (tid < 256) {
        int n = tid;
        int b = (int)(rowg0 >> 11);
        int c = (int)((rowg0 & 2047) >> LOG2L);
        float2 a = Apow[n];          // A^1
        float xr = 0.f, xi = 0.f;
#pragma unroll
        for (int j = 0; j < 16; ++j) {
            float ur = uB[j][n];
            float ui = uB[j][256 + n];
            float nr = fmaf(a.x, xr, fmaf(-a.y, xi, ur));
            float ni = fmaf(a.x, xi, fmaf(a.y, xr, ui));
            xr = nr; xi = ni;
            size_t rowg = rowg0 + j;
            xbb[rowg * 512 + n]       = f2b(xr);
            xbb[rowg * 512 + 256 + n] = f2b(xi);
        }
        carr[((size_t)b * NC + c) * N + n] = make_float2(xr, xi);
    }
}

// ---------------- K2: carry propagation (in-place: finals -> carry-ins) + x_last ----------------
__global__ __launch_bounds__(256) void k2_carry(const float* __restrict__ x0re,
                                                const float* __restrict__ x0im,
                                                const float2* __restrict__ Apow,
                                                float2* __restrict__ carr,
                                                float* __restrict__ out_tail,
                                                int tail_mode) {
    int b = blockIdx.x, n = threadIdx.x;
    float pr = x0re[b * N + n], pi = x0im[b * N + n];   // x[-1] = x0
    float2 aL = Apow[(L - 1) * N + n];                   // A^L
#pragma unroll 8
    for (int c = 0; c < NC; ++c) {
        size_t off = ((size_t)b * NC + c) * N + n;
        float2 f = carr[off];                 // chunk-final
        carr[off] = make_float2(pr, pi);      // carry-in for chunk c
        float nr = f.x + aL.x * pr - aL.y * pi;
        float ni = f.y + aL.x * pi + aL.y * pr;
        pr = nr; pi = ni;
    }
    if (tail_mode == 2) {
        out_tail[(b * N + n) * 2 + 0] = pr;
        out_tail[(b * N + n) * 2 + 1] = pi;
    } else if (tail_mode == 1) {
        out_tail[b * N + n] = pr;
    }
}

// ---------------- K3: MFMA GEMM, fused correction, B in LDS, 8 waves (rw x ch split) ----------------
// 512 thr: wave w -> row-group rw=w&3 (16 rows), col-half ch=w>>2 (4 ot-tiles).
// 10 phases x 2 ksteps, identical MFMA order per output -> bit-identical to r12.
__global__ __launch_bounds__(512, 2) void k3_mfma(const unsigned short* __restrict__ xbb,
                                                  const float2* __restrict__ Apow,
                                                  const float2* __restrict__ carr,
                                                  const float* __restrict__ u,
                                                  const unsigned short* __restrict__ Bswz,
                                                  const float* __restrict__ bias,
                                                  float* __restrict__ y) {
    __shared__ short8 Bs[2][1024];   // 2 buf x (2 ksteps x 8 ot x 64 lanes) x 16B = 32 KB
    int tid = threadIdx.x;
    int lane = tid & 63;
    int w = tid >> 6;
    int rw = w & 3;                  // row-group
    int ch = w >> 2;                 // column half (ot 0..3 or 4..7)
    size_t rowg = (size_t)blockIdx.x * 64 + rw * 16 + (lane & 15);
    int koff = (lane >> 4) * 8;
    int t = (int)(rowg & 2047);
    int b = (int)(rowg >> 11);
    int j = t & (L - 1);
    int c = t >> LOG2L;
    const float4* Ap4 = (const float4*)(Apow + (size_t)j * N);
    const float4* Cv4 = (const float4*)(carr + ((size_t)b * NC + c) * N);
    const unsigned short* arow = xbb + rowg * 512 + koff;
    const float* urow = u + rowg * INF + koff;
    const short8* Bfr = (const short8*)Bswz;

    f32x4 acc[4];
#pragma unroll
    for (int i = 0; i < 4; ++i) acc[i] = (f32x4){0.f, 0.f, 0.f, 0.f};

    auto KApair = [](int p, int& ka, int& kb) {
        if (p < 8) { ka = p; kb = p + 8; }
        else if (p == 8) { ka = 16; kb = 17; }
        else { ka = 18; kb = 19; }
    };

    short8 st[2];
    auto LOADB = [&](int p) {
        int ka, kb; KApair(p, ka, kb);
#pragma unroll
        for (int q = 0; q < 2; ++q) {
            int slot = tid * 2 + q;              // 0..1023
            int kk = slot >> 9;                  // 0: ka, 1: kb
            int rem = slot & 511;                // ot*64 + lane
            st[q] = Bfr[(size_t)(kk ? kb : ka) * 512 + rem];
        }
    };
    auto WRITEB = [&](int buf) {
#pragma unroll
        for (int q = 0; q < 2; ++q) Bs[buf][tid * 2 + q] = st[q];
    };

    LOADB(0);
    WRITEB(0);
    __syncthreads();

    int cur = 0;
    for (int p = 0; p < 10; ++p) {
        if (p < 9) LOADB(p + 1);                 // next phase's B in flight

        short8 afa, afb;                          // A-frags for ksteps (ka, kb)
        if (p < 8) {
            short8 xre = *(const short8*)(arow + p * 32);          // re, states n0..n0+7
            short8 xim = *(const short8*)(arow + (p + 8) * 32);    // im, same states
            int n0 = p * 32 + koff;
            float4 ap[4], vv[4];
#pragma unroll
            for (int q = 0; q < 4; ++q) {
                ap[q] = Ap4[(n0 >> 1) + q];       // A^(j+1) states n0+2q, n0+2q+1
                vv[q] = Cv4[(n0 >> 1) + q];       // carry   states n0+2q, n0+2q+1
            }
#pragma unroll
            for (int e = 0; e < 8; ++e) {
                float4 aq = ap[e >> 1];
                float4 vq = vv[e >> 1];
                float pr = (e & 1) ? aq.z : aq.x;
                float pi = (e & 1) ? aq.w : aq.y;
                float vr = (e & 1) ? vq.z : vq.x;
                float vi = (e & 1) ? vq.w : vq.y;
                afa[e] = (short)f2b(b2f((unsigned short)xre[e]) + (pr * vr - pi * vi));
                afb[e] = (short)f2b(b2f((unsigned short)xim[e]) + (pr * vi + pi * vr));
            }
        } else {
            int ks2a = (p == 8) ? 0 : 2;
            float4 a0 = *(const float4*)(urow + ks2a * 32);
            float4 a1 = *(const float4*)(urow + ks2a * 32 + 4);
            afa[0] = (short)f2b(a0.x); afa[1] = (short)f2b(a0.y);
            afa[2] = (short)f2b(a0.z); afa[3] = (short)f2b(a0.w);
            afa[4] = (short)f2b(a1.x); afa[5] = (short)f2b(a1.y);
            afa[6] = (short)f2b(a1.z); afa[7] = (short)f2b(a1.w);
            float4 b0 = *(const float4*)(urow + (ks2a + 1) * 32);
            float4 b1 = *(const float4*)(urow + (ks2a + 1) * 32 + 4);
            afb[0] = (short)f2b(b0.x); afb[1] = (short)f2b(b0.y);
            afb[2] = (short)f2b(b0.z); afb[3] = (short)f2b(b0.w);
            afb[4] = (short)f2b(b1.x); afb[5] = (short)f2b(b1.y);
            afb[6] = (short)f2b(b1.z); afb[7] = (short)f2b(b1.w);
        }

#pragma unroll
        for (int i = 0; i < 4; ++i) {
            short8 bf = Bs[cur][(ch * 4 + i) * 64 + lane];          // ds_read_b128
            acc[i] = __builtin_amdgcn_mfma_f32_16x16x32_bf16(afa, bf, acc[i], 0, 0, 0);
        }
#pragma unroll
        for (int i = 0; i < 4; ++i) {
            short8 bf = Bs[cur][512 + (ch * 4 + i) * 64 + lane];
            acc[i] = __builtin_amdgcn_mfma_f32_16x16x32_bf16(afb, bf, acc[i], 0, 0, 0);
        }

        __syncthreads();                         // all waves done reading Bs[cur]
        if (p < 9) WRITEB(cur ^ 1);              // safe: no one reads cur^1 now
        __syncthreads();                         // writes visible before next phase
        cur ^= 1;
    }

    int colb = lane & 15;
    int rq = lane >> 4;
    size_t rowout = (size_t)blockIdx.x * 64 + rw * 16 + rq * 4;
#pragma unroll
    for (int i = 0; i < 4; ++i) {
        int o = (ch * 4 + i) * 16 + colb;
        float bv = bias[o];
#pragma unroll
        for (int r = 0; r < 4; ++r) {
            y[(rowout + r) * OUTF + o] = acc[i][r] + bv;
        }
    }
}

extern "C" void kernel_launch(void* const* d_in, const int* in_sizes, int n_in,
                              void* d_out, int out_size, void* d_ws, size_t ws_size,
                              hipStream_t stream) {
    const float* u    = (const float*)d_in[0];
    const float* x0re = (const float*)d_in[1];
    const float* x0im = (const float*)d_in[2];
    const float* Are  = (const float*)d_in[3];
    const float* Aim  = (const float*)d_in[4];
    const float* Bre  = (const float*)d_in[5];
    const float* Bim  = (const float*)d_in[6];
    const float* Cre  = (const float*)d_in[7];
    const float* Cim  = (const float*)d_in[8];
    const float* D    = (const float*)d_in[9];
    const float* bias = (const float*)d_in[10];
    float* y = (float*)d_out;

    char* ws = (char*)d_ws;
    float2* Apow = (float2*)ws;                                    // 32 KB
    char* p = ws + (size_t)L * N * sizeof(float2);
    float2* carr = (float2*)p;                                     // 2 MB
    p += (size_t)BATCH * NC * N * sizeof(float2);
    unsigned short* xbb = (unsigned short*)p;                      // 16 MB bf16 [row][re256|im256]
    p += (size_t)BATCH * T * 512 * sizeof(unsigned short);
    unsigned short* Bswz = (unsigned short*)p;                     // 160 KB (C-hat frags)
    p += (size_t)NKS * 8 * 64 * 8 * sizeof(unsigned short);
    unsigned short* Bswz2 = (unsigned short*)p;                    // 128 KB (Bh frags)

    const int ysz = BATCH * T * OUTF;
    const int tail_elems = out_size - ysz;
    int tail_mode = (tail_elems >= BATCH * N * 2) ? 2
                  : (tail_elems >= BATCH * N) ? 1 : 0;
    float* tail = y + ysz;

    k_prep<<<73, 256, 0, stream>>>(Are, Aim, Bre, Bim, Cre, Cim, D, Apow, Bswz, Bswz2);
    kU_scan<<<BATCH * NC, 512, 0, stream>>>(u, Bswz2, Apow, xbb, carr);
    k2_carry<<<BATCH, 256, 0, stream>>>(x0re, x0im, Apow, carr, tail, tail_mode);
    k3_mfma<<<(BATCH * T) / 64, 512, 0, stream>>>(xbb, Apow, carr, u, Bswz, bias, y);
}

// Round 14
// 55.118 us; speedup vs baseline: 1.0883x; 1.0883x over previous
//
#include <hip/hip_runtime.h>
#include <math.h>

#define BATCH 8
#define T 2048
#define N 256        // STATE
#define INF 128      // IN
#define OUTF 128     // OUT
#define L 16         // chunk length
#define LOG2L 4
#define NC (T / L)   // 128 chunks
#define KTOT 640     // K for k3 = 256 (Xr) + 256 (Xi) + 128 (u)
#define NKS 20       // KTOT / 32  (C-hat K-steps)
#define NKU 4        // INF / 32   (Bh K-steps)
#define UBS 516      // padded fp32 col-stride for kU uB tile

typedef __attribute__((ext_vector_type(8))) short short8;
typedef __attribute__((ext_vector_type(4))) float f32x4;

__device__ __forceinline__ unsigned short f2b(float f) {   // fp32 -> bf16 RTNE
    union { float f; unsigned u; } x; x.f = f;
    unsigned r = (x.u + 0x7FFFu + ((x.u >> 16) & 1u)) >> 16;
    return (unsigned short)r;
}
__device__ __forceinline__ float b2f(unsigned short s) {
    union { unsigned u; float f; } x; x.u = ((unsigned)s) << 16;
    return x.f;
}

// ---------------- K_PREP: Apow + C-hat frags (Bswz) + Bh frags (Bswz2) ----------------
__global__ __launch_bounds__(256) void k_prep(const float* __restrict__ Are,
                                              const float* __restrict__ Aim,
                                              const float* __restrict__ Bre,
                                              const float* __restrict__ Bim,
                                              const float* __restrict__ Cre,
                                              const float* __restrict__ Cim,
                                              const float* __restrict__ D,
                                              float2* __restrict__ Apow,
                                              unsigned short* __restrict__ Bswz,
                                              unsigned short* __restrict__ Bswz2) {
    int blk = blockIdx.x;
    int tid = threadIdx.x;
    if (blk < 40) {
        int unit = blk * 4 + (tid >> 6);     // 0..159 = ks*8 + ot
        int ks = unit >> 3, ot = unit & 7;
        int l = tid & 63;
        int o = ot * 16 + (l & 15);
        int k0 = ks * 32 + (l >> 4) * 8;
        short8 out;
#pragma unroll
        for (int j = 0; j < 8; ++j) {
            int gk = k0 + j;
            float v = (gk < 256) ? Cre[gk * OUTF + o]
                    : (gk < 512) ? -Cim[(gk - 256) * OUTF + o]
                                 : D[(gk - 512) * OUTF + o];
            out[j] = (short)f2b(v);
        }
        *(short8*)(Bswz + ((size_t)unit * 64 + l) * 8) = out;
    } else if (blk < 72) {
        int unit = (blk - 40) * 4 + (tid >> 6);   // 0..127 = ks*32 + ct
        int l = tid & 63;
        int col = (unit & 31) * 16 + (l & 15);
        int k0 = (unit >> 5) * 32 + (l >> 4) * 8;
        short8 out;
#pragma unroll
        for (int j = 0; j < 8; ++j) {
            int gk = k0 + j;
            float v = (col < 256) ? Bre[gk * N + col] : Bim[gk * N + col - 256];
            out[j] = (short)f2b(v);
        }
        *(short8*)(Bswz2 + ((size_t)unit * 64 + l) * 8) = out;
    } else {
        int n = tid;
        float ar = Are[n], ai = Aim[n];
        float inv = 1.0f / sqrtf(ar * ar + ai * ai + 1.0f);
        ar *= inv; ai *= inv;
        float pr = ar, pi = ai;
        for (int j = 0; j < L; ++j) {
            Apow[j * N + n] = make_float2(pr, pi);   // A^(j+1)
            float nr = pr * ar - pi * ai;
            float ni = pr * ai + pi * ar;
            pr = nr; pi = ni;
        }
    }
}

// ---------------- KU: uB = u @ Bh via MFMA, then chunk-local scan ----------------
// grid 1024 blocks x 512 threads (8 waves). Block = ONE chunk: 16 rows x 512 cols.
__global__ __launch_bounds__(512, 8) void kU_scan(const float* __restrict__ u,
                                                  const unsigned short* __restrict__ Bswz2,
                                                  const float2* __restrict__ Apow,
                                                  unsigned short* __restrict__ xbb,
                                                  float2* __restrict__ carr) {
    __shared__ float uB[16][UBS];      // 33 KB
    int tid = threadIdx.x;
    int lane = tid & 63;
    int w = tid >> 6;
    size_t rowg0 = (size_t)blockIdx.x * 16;          // chunk start row
    const float* uprow = u + (rowg0 + (lane & 15)) * INF + (lane >> 4) * 8;

    f32x4 acc[4];
#pragma unroll
    for (int i = 0; i < 4; ++i) acc[i] = (f32x4){0.f, 0.f, 0.f, 0.f};

    const short8* Bfr2 = (const short8*)Bswz2;
#pragma unroll
    for (int ks = 0; ks < NKU; ++ks) {
        float4 a0 = *(const float4*)(uprow + ks * 32);
        float4 a1 = *(const float4*)(uprow + ks * 32 + 4);
        short8 af;
        af[0] = (short)f2b(a0.x); af[1] = (short)f2b(a0.y);
        af[2] = (short)f2b(a0.z); af[3] = (short)f2b(a0.w);
        af[4] = (short)f2b(a1.x); af[5] = (short)f2b(a1.y);
        af[6] = (short)f2b(a1.z); af[7] = (short)f2b(a1.w);
#pragma unroll
        for (int i = 0; i < 4; ++i) {
            int ct = w * 4 + i;
            short8 bf = Bfr2[(size_t)(ks * 32 + ct) * 64 + lane];
            acc[i] = __builtin_amdgcn_mfma_f32_16x16x32_bf16(af, bf, acc[i], 0, 0, 0);
        }
    }
    {   // spill: C/D layout row = (lane>>4)*4 + r, col = tile*16 + (lane&15)
        int rbase = (lane >> 4) * 4;
        int cb = lane & 15;
#pragma unroll
        for (int i = 0; i < 4; ++i) {
            int col = (w * 4 + i) * 16 + cb;
#pragma unroll
            for (int r = 0; r < 4; ++r)
                uB[rbase + r][col] = acc[i][r];
        }
    }
    __syncthreads();

    if (tid < 256) {
        int n = tid;
        int b = (int)(rowg0 >> 11);
        int c = (int)((rowg0 & 2047) >> LOG2L);
        float2 a = Apow[n];          // A^1
        float xr = 0.f, xi = 0.f;
#pragma unroll
        for (int j = 0; j < 16; ++j) {
            float ur = uB[j][n];
            float ui = uB[j][256 + n];
            float nr = fmaf(a.x, xr, fmaf(-a.y, xi, ur));
            float ni = fmaf(a.x, xi, fmaf(a.y, xr, ui));
            xr = nr; xi = ni;
            size_t rowg = rowg0 + j;
            xbb[rowg * 512 + n]       = f2b(xr);
            xbb[rowg * 512 + 256 + n] = f2b(xi);
        }
        carr[((size_t)b * NC + c) * N + n] = make_float2(xr, xi);
    }
}

// ---------------- K2: carry propagation (in-place: finals -> carry-ins) + x_last ----------------
__global__ __launch_bounds__(256) void k2_carry(const float* __restrict__ x0re,
                                                const float* __restrict__ x0im,
                                                const float2* __restrict__ Apow,
                                                float2* __restrict__ carr,
                                                float* __restrict__ out_tail,
                                                int tail_mode) {
    int b = blockIdx.x, n = threadIdx.x;
    float pr = x0re[b * N + n], pi = x0im[b * N + n];   // x[-1] = x0
    float2 aL = Apow[(L - 1) * N + n];                   // A^L
#pragma unroll 8
    for (int c = 0; c < NC; ++c) {
        size_t off = ((size_t)b * NC + c) * N + n;
        float2 f = carr[off];                 // chunk-final
        carr[off] = make_float2(pr, pi);      // carry-in for chunk c
        float nr = f.x + aL.x * pr - aL.y * pi;
        float ni = f.y + aL.x * pi + aL.y * pr;
        pr = nr; pi = ni;
    }
    if (tail_mode == 2) {
        out_tail[(b * N + n) * 2 + 0] = pr;
        out_tail[(b * N + n) * 2 + 1] = pi;
    } else if (tail_mode == 1) {
        out_tail[b * N + n] = pr;
    }
}

// ---------------- K3: MFMA GEMM (r12 structure), B staged via global_load_lds, 1 barrier/phase ----
// 10 phases x 2 ksteps: p<8 -> (ks=p re, ks=p+8 im); p=8 -> u ksteps 16,17; p=9 -> 18,19.
// grid 256 x 256 thr (4 waves). Bs slot s of phase region = Bfr[k*512 + s] (linear copy),
// so global_load_lds (wave-uniform LDS base + lane*16) matches exactly: wave w, seg i
// covers bytes (w*4+i)*1024 of the 16 KB region.
__global__ __launch_bounds__(256) void k3_mfma(const unsigned short* __restrict__ xbb,
                                               const float2* __restrict__ Apow,
                                               const float2* __restrict__ carr,
                                               const float* __restrict__ u,
                                               const unsigned short* __restrict__ Bswz,
                                               const float* __restrict__ bias,
                                               float* __restrict__ y) {
    __shared__ short8 Bs[2][1024];   // 2 buf x 16 KB
    int tid = threadIdx.x;
    int lane = tid & 63;
    int w = tid >> 6;
    size_t rowg = (size_t)blockIdx.x * 64 + w * 16 + (lane & 15);
    int koff = (lane >> 4) * 8;
    int t = (int)(rowg & 2047);
    int b = (int)(rowg >> 11);
    int j = t & (L - 1);
    int c = t >> LOG2L;
    const float4* Ap4 = (const float4*)(Apow + (size_t)j * N);
    const float4* Cv4 = (const float4*)(carr + ((size_t)b * NC + c) * N);
    const unsigned short* arow = xbb + rowg * 512 + koff;
    const float* urow = u + rowg * INF + koff;
    const char* Bbytes = (const char*)Bswz;

    f32x4 acc[8];
#pragma unroll
    for (int ot = 0; ot < 8; ++ot) acc[ot] = (f32x4){0.f, 0.f, 0.f, 0.f};

    auto KApair = [](int p, int& ka, int& kb) {
        if (p < 8) { ka = p; kb = p + 8; }
        else if (p == 8) { ka = 16; kb = 17; }
        else { ka = 18; kb = 19; }
    };

    // async-stage phase p's 16 KB B region into Bs[buf]
    auto STAGEB = [&](int p, int buf) {
        int ka, kb; KApair(p, ka, kb);
#pragma unroll
        for (int i = 0; i < 4; ++i) {
            int seg = w * 4 + i;                       // 0..15, 1 KB each
            int k = (seg < 8) ? ka : kb;
            const char* src = Bbytes + (size_t)k * 8192 + (size_t)(seg & 7) * 1024 + (size_t)lane * 16;
            __builtin_amdgcn_global_load_lds(
                (const __attribute__((address_space(1))) unsigned int*)src,
                (__attribute__((address_space(3))) unsigned int*)((char*)&Bs[buf][0] + seg * 1024),
                16, 0, 0);
        }
    };

    STAGEB(0, 0);
    __syncthreads();                 // drains vmcnt -> Bs[0] ready

    int cur = 0;
    for (int p = 0; p < 10; ++p) {
        if (p < 9) STAGEB(p + 1, cur ^ 1);    // async into other buffer

        short8 afa, afb;                       // A-frags for ksteps (ka, kb)
        if (p < 8) {
            short8 xre = *(const short8*)(arow + p * 32);          // re, states n0..n0+7
            short8 xim = *(const short8*)(arow + (p + 8) * 32);    // im, same states
            int n0 = p * 32 + koff;
            float4 ap[4], vv[4];
#pragma unroll
            for (int q = 0; q < 4; ++q) {
                ap[q] = Ap4[(n0 >> 1) + q];       // A^(j+1) states n0+2q, n0+2q+1
                vv[q] = Cv4[(n0 >> 1) + q];       // carry   states n0+2q, n0+2q+1
            }
#pragma unroll
            for (int e = 0; e < 8; ++e) {
                float4 aq = ap[e >> 1];
                float4 vq = vv[e >> 1];
                float pr = (e & 1) ? aq.z : aq.x;
                float pi = (e & 1) ? aq.w : aq.y;
                float vr = (e & 1) ? vq.z : vq.x;
                float vi = (e & 1) ? vq.w : vq.y;
                afa[e] = (short)f2b(b2f((unsigned short)xre[e]) + (pr * vr - pi * vi));
                afb[e] = (short)f2b(b2f((unsigned short)xim[e]) + (pr * vi + pi * vr));
            }
        } else {
            int ks2a = (p == 8) ? 0 : 2;
            float4 a0 = *(const float4*)(urow + ks2a * 32);
            float4 a1 = *(const float4*)(urow + ks2a * 32 + 4);
            afa[0] = (short)f2b(a0.x); afa[1] = (short)f2b(a0.y);
            afa[2] = (short)f2b(a0.z); afa[3] = (short)f2b(a0.w);
            afa[4] = (short)f2b(a1.x); afa[5] = (short)f2b(a1.y);
            afa[6] = (short)f2b(a1.z); afa[7] = (short)f2b(a1.w);
            float4 b0 = *(const float4*)(urow + (ks2a + 1) * 32);
            float4 b1 = *(const float4*)(urow + (ks2a + 1) * 32 + 4);
            afb[0] = (short)f2b(b0.x); afb[1] = (short)f2b(b0.y);
            afb[2] = (short)f2b(b0.z); afb[3] = (short)f2b(b0.w);
            afb[4] = (short)f2b(b1.x); afb[5] = (short)f2b(b1.y);
            afb[6] = (short)f2b(b1.z); afb[7] = (short)f2b(b1.w);
        }

#pragma unroll
        for (int ot = 0; ot < 8; ++ot) {
            short8 bf = Bs[cur][ot * 64 + lane];           // ds_read_b128, conflict-free
            acc[ot] = __builtin_amdgcn_mfma_f32_16x16x32_bf16(afa, bf, acc[ot], 0, 0, 0);
        }
#pragma unroll
        for (int ot = 0; ot < 8; ++ot) {
            short8 bf = Bs[cur][512 + ot * 64 + lane];
            acc[ot] = __builtin_amdgcn_mfma_f32_16x16x32_bf16(afb, bf, acc[ot], 0, 0, 0);
        }

        __syncthreads();     // all waves done reading Bs[cur]; drains loads into cur^1
        cur ^= 1;
    }

    int colb = lane & 15;
    int rq = lane >> 4;
    size_t rowout = (size_t)blockIdx.x * 64 + w * 16 + rq * 4;
#pragma unroll
    for (int ot = 0; ot < 8; ++ot) {
        int o = ot * 16 + colb;
        float bv = bias[o];
#pragma unroll
        for (int r = 0; r < 4; ++r) {
            y[(rowout + r) * OUTF + o] = acc[ot][r] + bv;
        }
    }
}

extern "C" void kernel_launch(void* const* d_in, const int* in_sizes, int n_in,
                              void* d_out, int out_size, void* d_ws, size_t ws_size,
                              hipStream_t stream) {
    const float* u    = (const float*)d_in[0];
    const float* x0re = (const float*)d_in[1];
    const float* x0im = (const float*)d_in[2];
    const float* Are  = (const float*)d_in[3];
    const float* Aim  = (const float*)d_in[4];
    const float* Bre  = (const float*)d_in[5];
    const float* Bim  = (const float*)d_in[6];
    const float* Cre  = (const float*)d_in[7];
    const float* Cim  = (const float*)d_in[8];
    const float* D    = (const float*)d_in[9];
    const float* bias = (const float*)d_in[10];
    float* y = (float*)d_out;

    char* ws = (char*)d_ws;
    float2* Apow = (float2*)ws;                                    // 32 KB
    char* p = ws + (size_t)L * N * sizeof(float2);
    float2* carr = (float2*)p;                                     // 2 MB
    p += (size_t)BATCH * NC * N * sizeof(float2);
    unsigned short* xbb = (unsigned short*)p;                      // 16 MB bf16 [row][re256|im256]
    p += (size_t)BATCH * T * 512 * sizeof(unsigned short);
    unsigned short* Bswz = (unsigned short*)p;                     // 160 KB (C-hat frags)
    p += (size_t)NKS * 8 * 64 * 8 * sizeof(unsigned short);
    unsigned short* Bswz2 = (unsigned short*)p;                    // 128 KB (Bh frags)

    const int ysz = BATCH * T * OUTF;
    const int tail_elems = out_size - ysz;
    int tail_mode = (tail_elems >= BATCH * N * 2) ? 2
                  : (tail_elems >= BATCH * N) ? 1 : 0;
    float* tail = y + ysz;

    k_prep<<<73, 256, 0, stream>>>(Are, Aim, Bre, Bim, Cre, Cim, D, Apow, Bswz, Bswz2);
    kU_scan<<<BATCH * NC, 512, 0, stream>>>(u, Bswz2, Apow, xbb, carr);
    k2_carry<<<BATCH, 256, 0, stream>>>(x0re, x0im, Apow, carr, tail, tail_mode);
    k3_mfma<<<(BATCH * T) / 64, 256, 0, stream>>>(xbb, Apow, carr, u, Bswz, bias, y);
}

// Round 15
// 54.452 us; speedup vs baseline: 1.1016x; 1.0122x over previous
//
#include <hip/hip_runtime.h>
#include <math.h>

#define BATCH 8
#define T 2048
#define N 256        // STATE
#define INF 128      // IN
#define OUTF 128     // OUT
#define L 16         // chunk length
#define LOG2L 4
#define NC (T / L)   // 128 chunks
#define KTOT 640     // K for k3 = 256 (Xr) + 256 (Xi) + 128 (u)
#define NKS 20       // KTOT / 32  (C-hat K-steps)
#define NKU 4        // INF / 32   (Bh K-steps)
#define UBS 516      // padded fp32 col-stride for kU uB tile

typedef __attribute__((ext_vector_type(8))) short short8;
typedef __attribute__((ext_vector_type(4))) float f32x4;

__device__ __forceinline__ unsigned short f2b(float f) {   // fp32 -> bf16 RTNE
    union { float f; unsigned u; } x; x.f = f;
    unsigned r = (x.u + 0x7FFFu + ((x.u >> 16) & 1u)) >> 16;
    return (unsigned short)r;
}
__device__ __forceinline__ float b2f(unsigned short s) {
    union { unsigned u; float f; } x; x.u = ((unsigned)s) << 16;
    return x.f;
}

// ---------------- K_PREP: Apow + C-hat frags (Bswz) + Bh frags (Bswz2) ----------------
__global__ __launch_bounds__(256) void k_prep(const float* __restrict__ Are,
                                              const float* __restrict__ Aim,
                                              const float* __restrict__ Bre,
                                              const float* __restrict__ Bim,
                                              const float* __restrict__ Cre,
                                              const float* __restrict__ Cim,
                                              const float* __restrict__ D,
                                              float2* __restrict__ Apow,
                                              unsigned short* __restrict__ Bswz,
                                              unsigned short* __restrict__ Bswz2) {
    int blk = blockIdx.x;
    int tid = threadIdx.x;
    if (blk < 40) {
        int unit = blk * 4 + (tid >> 6);     // 0..159 = ks*8 + ot
        int ks = unit >> 3, ot = unit & 7;
        int l = tid & 63;
        int o = ot * 16 + (l & 15);
        int k0 = ks * 32 + (l >> 4) * 8;
        short8 out;
#pragma unroll
        for (int j = 0; j < 8; ++j) {
            int gk = k0 + j;
            float v = (gk < 256) ? Cre[gk * OUTF + o]
                    : (gk < 512) ? -Cim[(gk - 256) * OUTF + o]
                                 : D[(gk - 512) * OUTF + o];
            out[j] = (short)f2b(v);
        }
        *(short8*)(Bswz + ((size_t)unit * 64 + l) * 8) = out;
    } else if (blk < 72) {
        int unit = (blk - 40) * 4 + (tid >> 6);   // 0..127 = ks*32 + ct
        int l = tid & 63;
        int col = (unit & 31) * 16 + (l & 15);
        int k0 = (unit >> 5) * 32 + (l >> 4) * 8;
        short8 out;
#pragma unroll
        for (int j = 0; j < 8; ++j) {
            int gk = k0 + j;
            float v = (col < 256) ? Bre[gk * N + col] : Bim[gk * N + col - 256];
            out[j] = (short)f2b(v);
        }
        *(short8*)(Bswz2 + ((size_t)unit * 64 + l) * 8) = out;
    } else {
        int n = tid;
        float ar = Are[n], ai = Aim[n];
        float inv = 1.0f / sqrtf(ar * ar + ai * ai + 1.0f);
        ar *= inv; ai *= inv;
        float pr = ar, pi = ai;
        for (int j = 0; j < L; ++j) {
            Apow[j * N + n] = make_float2(pr, pi);   // A^(j+1)
            float nr = pr * ar - pi * ai;
            float ni = pr * ai + pi * ar;
            pr = nr; pi = ni;
        }
    }
}

// ---------------- KU: uB = u @ Bh via MFMA, scan in LDS, wide bf16 stores ----------------
// grid 1024 blocks x 512 threads (8 waves). Block = ONE chunk: 16 rows x 512 cols.
__global__ __launch_bounds__(512, 8) void kU_scan(const float* __restrict__ u,
                                                  const unsigned short* __restrict__ Bswz2,
                                                  const float2* __restrict__ Apow,
                                                  unsigned short* __restrict__ xbb,
                                                  float2* __restrict__ carr) {
    __shared__ float uB[16][UBS];      // 33 KB
    int tid = threadIdx.x;
    int lane = tid & 63;
    int w = tid >> 6;
    size_t rowg0 = (size_t)blockIdx.x * 16;          // chunk start row
    const float* uprow = u + (rowg0 + (lane & 15)) * INF + (lane >> 4) * 8;

    f32x4 acc[4];
#pragma unroll
    for (int i = 0; i < 4; ++i) acc[i] = (f32x4){0.f, 0.f, 0.f, 0.f};

    const short8* Bfr2 = (const short8*)Bswz2;
#pragma unroll
    for (int ks = 0; ks < NKU; ++ks) {
        float4 a0 = *(const float4*)(uprow + ks * 32);
        float4 a1 = *(const float4*)(uprow + ks * 32 + 4);
        short8 af;
        af[0] = (short)f2b(a0.x); af[1] = (short)f2b(a0.y);
        af[2] = (short)f2b(a0.z); af[3] = (short)f2b(a0.w);
        af[4] = (short)f2b(a1.x); af[5] = (short)f2b(a1.y);
        af[6] = (short)f2b(a1.z); af[7] = (short)f2b(a1.w);
#pragma unroll
        for (int i = 0; i < 4; ++i) {
            int ct = w * 4 + i;
            short8 bf = Bfr2[(size_t)(ks * 32 + ct) * 64 + lane];
            acc[i] = __builtin_amdgcn_mfma_f32_16x16x32_bf16(af, bf, acc[i], 0, 0, 0);
        }
    }
    {   // spill: C/D layout row = (lane>>4)*4 + r, col = tile*16 + (lane&15)
        int rbase = (lane >> 4) * 4;
        int cb = lane & 15;
#pragma unroll
        for (int i = 0; i < 4; ++i) {
            int col = (w * 4 + i) * 16 + cb;
#pragma unroll
            for (int r = 0; r < 4; ++r)
                uB[rbase + r][col] = acc[i][r];
        }
    }
    __syncthreads();

    if (tid < 256) {
        int n = tid;
        int b = (int)(rowg0 >> 11);
        int c = (int)((rowg0 & 2047) >> LOG2L);
        float2 a = Apow[n];          // A^1
        float xr = 0.f, xi = 0.f;
#pragma unroll
        for (int j = 0; j < 16; ++j) {
            float ur = uB[j][n];
            float ui = uB[j][256 + n];
            float nr = fmaf(a.x, xr, fmaf(-a.y, xi, ur));
            float ni = fmaf(a.x, xi, fmaf(a.y, xr, ui));
            xr = nr; xi = ni;
            uB[j][n] = xr;             // overwrite in place (each n owned by one thread)
            uB[j][256 + n] = xi;
        }
        carr[((size_t)b * NC + c) * N + n] = make_float2(xr, xi);
    }
    __syncthreads();

    // wide copy LDS fp32 -> xbb bf16: thread (row = tid&15, colgroup = tid>>4)
    {
        int row = tid & 15;
        int cg  = tid >> 4;              // 0..31
#pragma unroll
        for (int half = 0; half < 2; ++half) {
            int col0 = half * 256 + cg * 8;
            const float4* s4 = (const float4*)&uB[row][col0];
            float4 v0 = s4[0];
            float4 v1 = s4[1];
            short8 st;
            st[0] = (short)f2b(v0.x); st[1] = (short)f2b(v0.y);
            st[2] = (short)f2b(v0.z); st[3] = (short)f2b(v0.w);
            st[4] = (short)f2b(v1.x); st[5] = (short)f2b(v1.y);
            st[6] = (short)f2b(v1.z); st[7] = (short)f2b(v1.w);
            *(short8*)(xbb + (rowg0 + row) * 512 + col0) = st;
        }
    }
}

// ---------------- K2: carry propagation (in-place: finals -> carry-ins) + x_last ----------------
__global__ __launch_bounds__(256) void k2_carry(const float* __restrict__ x0re,
                                                const float* __restrict__ x0im,
                                                const float2* __restrict__ Apow,
                                                float2* __restrict__ carr,
                                                float* __restrict__ out_tail,
                                                int tail_mode) {
    int b = blockIdx.x, n = threadIdx.x;
    float pr = x0re[b * N + n], pi = x0im[b * N + n];   // x[-1] = x0
    float2 aL = Apow[(L - 1) * N + n];                   // A^L
#pragma unroll 8
    for (int c = 0; c < NC; ++c) {
        size_t off = ((size_t)b * NC + c) * N + n;
        float2 f = carr[off];                 // chunk-final
        carr[off] = make_float2(pr, pi);      // carry-in for chunk c
        float nr = f.x + aL.x * pr - aL.y * pi;
        float ni = f.y + aL.x * pi + aL.y * pr;
        pr = nr; pi = ni;
    }
    if (tail_mode == 2) {
        out_tail[(b * N + n) * 2 + 0] = pr;
        out_tail[(b * N + n) * 2 + 1] = pi;
    } else if (tail_mode == 1) {
        out_tail[b * N + n] = pr;
    }
}

// ---------------- K3: MFMA GEMM, fused correction, B via global_load_lds dbuf,
//                  A-side register prefetch one phase ahead ----------------
__global__ __launch_bounds__(256) void k3_mfma(const unsigned short* __restrict__ xbb,
                                               const float2* __restrict__ Apow,
                                               const float2* __restrict__ carr,
                                               const float* __restrict__ u,
                                               const unsigned short* __restrict__ Bswz,
                                               const float* __restrict__ bias,
                                               float* __restrict__ y) {
    __shared__ short8 Bs[2][1024];   // 2 buf x 16 KB
    int tid = threadIdx.x;
    int lane = tid & 63;
    int w = tid >> 6;
    size_t rowg = (size_t)blockIdx.x * 64 + w * 16 + (lane & 15);
    int koff = (lane >> 4) * 8;
    int t = (int)(rowg & 2047);
    int b = (int)(rowg >> 11);
    int j = t & (L - 1);
    int c = t >> LOG2L;
    const float4* Ap4 = (const float4*)(Apow + (size_t)j * N);
    const float4* Cv4 = (const float4*)(carr + ((size_t)b * NC + c) * N);
    const unsigned short* arow = xbb + rowg * 512 + koff;
    const float* urow = u + rowg * INF + koff;
    const char* Bbytes = (const char*)Bswz;

    f32x4 acc[8];
#pragma unroll
    for (int ot = 0; ot < 8; ++ot) acc[ot] = (f32x4){0.f, 0.f, 0.f, 0.f};

    auto KApair = [](int p, int& ka, int& kb) {
        if (p < 8) { ka = p; kb = p + 8; }
        else if (p == 8) { ka = 16; kb = 17; }
        else { ka = 18; kb = 19; }
    };

    // async-stage phase p's 16 KB B region into Bs[buf]
    auto STAGEB = [&](int p, int buf) {
        int ka, kb; KApair(p, ka, kb);
#pragma unroll
        for (int i = 0; i < 4; ++i) {
            int seg = w * 4 + i;                       // 0..15, 1 KB each
            int k = (seg < 8) ? ka : kb;
            const char* src = Bbytes + (size_t)k * 8192 + (size_t)(seg & 7) * 1024 + (size_t)lane * 16;
            __builtin_amdgcn_global_load_lds(
                (const __attribute__((address_space(1))) unsigned int*)src,
                (__attribute__((address_space(3))) unsigned int*)((char*)&Bs[buf][0] + seg * 1024),
                16, 0, 0);
        }
    };

    // prefetched A-side registers
    short8 xre, xim;
    float4 ap0, ap1, ap2, ap3, vv0, vv1, vv2, vv3;
    float4 ua0, ua1, ub0, ub1;

    auto LOADX = [&](int p) {          // p in 0..7
        xre = *(const short8*)(arow + p * 32);
        xim = *(const short8*)(arow + (p + 8) * 32);
        int f4 = (p * 32 + koff) >> 1;
        ap0 = Ap4[f4];     ap1 = Ap4[f4 + 1]; ap2 = Ap4[f4 + 2]; ap3 = Ap4[f4 + 3];
        vv0 = Cv4[f4];     vv1 = Cv4[f4 + 1]; vv2 = Cv4[f4 + 2]; vv3 = Cv4[f4 + 3];
    };
    auto LOADU = [&](int p) {          // p = 8 or 9
        int k = (p == 8) ? 0 : 2;
        ua0 = *(const float4*)(urow + k * 32);
        ua1 = *(const float4*)(urow + k * 32 + 4);
        ub0 = *(const float4*)(urow + (k + 1) * 32);
        ub1 = *(const float4*)(urow + (k + 1) * 32 + 4);
    };

    STAGEB(0, 0);
    LOADX(0);
    __syncthreads();                 // drains vmcnt -> Bs[0] ready

    int cur = 0;
    for (int p = 0; p < 10; ++p) {
        if (p < 9) STAGEB(p + 1, cur ^ 1);    // async into other buffer

        short8 afa, afb;                       // A-frags for ksteps (ka, kb)
        if (p < 8) {
            float4 ap[4] = {ap0, ap1, ap2, ap3};
            float4 vv[4] = {vv0, vv1, vv2, vv3};
#pragma unroll
            for (int e = 0; e < 8; ++e) {
                float4 aq = ap[e >> 1];
                float4 vq = vv[e >> 1];
                float pr = (e & 1) ? aq.z : aq.x;
                float pi = (e & 1) ? aq.w : aq.y;
                float vr = (e & 1) ? vq.z : vq.x;
                float vi = (e & 1) ? vq.w : vq.y;
                afa[e] = (short)f2b(b2f((unsigned short)xre[e]) + (pr * vr - pi * vi));
                afb[e] = (short)f2b(b2f((unsigned short)xim[e]) + (pr * vi + pi * vr));
            }
        } else {
            afa[0] = (short)f2b(ua0.x); afa[1] = (short)f2b(ua0.y);
            afa[2] = (short)f2b(ua0.z); afa[3] = (short)f2b(ua0.w);
            afa[4] = (short)f2b(ua1.x); afa[5] = (short)f2b(ua1.y);
            afa[6] = (short)f2b(ua1.z); afa[7] = (short)f2b(ua1.w);
            afb[0] = (short)f2b(ub0.x); afb[1] = (short)f2b(ub0.y);
            afb[2] = (short)f2b(ub0.z); afb[3] = (short)f2b(ub0.w);
            afb[4] = (short)f2b(ub1.x); afb[5] = (short)f2b(ub1.y);
            afb[6] = (short)f2b(ub1.z); afb[7] = (short)f2b(ub1.w);
        }

        // prefetch next phase's A-side (current regs consumed into afa/afb)
        if (p < 7)      LOADX(p + 1);
        else if (p < 9) LOADU(p + 1);

#pragma unroll
        for (int ot = 0; ot < 8; ++ot) {
            short8 bf = Bs[cur][ot * 64 + lane];           // ds_read_b128, conflict-free
            acc[ot] = __builtin_amdgcn_mfma_f32_16x16x32_bf16(afa, bf, acc[ot], 0, 0, 0);
        }
#pragma unroll
        for (int ot = 0; ot < 8; ++ot) {
            short8 bf = Bs[cur][512 + ot * 64 + lane];
            acc[ot] = __builtin_amdgcn_mfma_f32_16x16x32_bf16(afb, bf, acc[ot], 0, 0, 0);
        }

        __syncthreads();     // all waves done reading Bs[cur]; drains loads into cur^1
        cur ^= 1;
    }

    int colb = lane & 15;
    int rq = lane >> 4;
    size_t rowout = (size_t)blockIdx.x * 64 + w * 16 + rq * 4;
#pragma unroll
    for (int ot = 0; ot < 8; ++ot) {
        int o = ot * 16 + colb;
        float bv = bias[o];
#pragma unroll
        for (int r = 0; r < 4; ++r) {
            y[(rowout + r) * OUTF + o] = acc[ot][r] + bv;
        }
    }
}

extern "C" void kernel_launch(void* const* d_in, const int* in_sizes, int n_in,
                              void* d_out, int out_size, void* d_ws, size_t ws_size,
                              hipStream_t stream) {
    const float* u    = (const float*)d_in[0];
    const float* x0re = (const float*)d_in[1];
    const float* x0im = (const float*)d_in[2];
    const float* Are  = (const float*)d_in[3];
    const float* Aim  = (const float*)d_in[4];
    const float* Bre  = (const float*)d_in[5];
    const float* Bim  = (const float*)d_in[6];
    const float* Cre  = (const float*)d_in[7];
    const float* Cim  = (const float*)d_in[8];
    const float* D    = (const float*)d_in[9];
    const float* bias = (const float*)d_in[10];
    float* y = (float*)d_out;

    char* ws = (char*)d_ws;
    float2* Apow = (float2*)ws;                                    // 32 KB
    char* p = ws + (size_t)L * N * sizeof(float2);
    float2* carr = (float2*)p;                                     // 2 MB
    p += (size_t)BATCH * NC * N * sizeof(float2);
    unsigned short* xbb = (unsigned short*)p;                      // 16 MB bf16 [row][re256|im256]
    p += (size_t)BATCH * T * 512 * sizeof(unsigned short);
    unsigned short* Bswz = (unsigned short*)p;                     // 160 KB (C-hat frags)
    p += (size_t)NKS * 8 * 64 * 8 * sizeof(unsigned short);
    unsigned short* Bswz2 = (unsigned short*)p;                    // 128 KB (Bh frags)

    const int ysz = BATCH * T * OUTF;
    const int tail_elems = out_size - ysz;
    int tail_mode = (tail_elems >= BATCH * N * 2) ? 2
                  : (tail_elems >= BATCH * N) ? 1 : 0;
    float* tail = y + ysz;

    k_prep<<<73, 256, 0, stream>>>(Are, Aim, Bre, Bim, Cre, Cim, D, Apow, Bswz, Bswz2);
    kU_scan<<<BATCH * NC, 512, 0, stream>>>(u, Bswz2, Apow, xbb, carr);
    k2_carry<<<BATCH, 256, 0, stream>>>(x0re, x0im, Apow, carr, tail, tail_mode);
    k3_mfma<<<(BATCH * T) / 64, 256, 0, stream>>>(xbb, Apow, carr, u, Bswz, bias, y);
}